// Round 2
// baseline (111151.892 us; speedup 1.0000x reference)
//
#include <hip/hip_runtime.h>
#include <hip/hip_cooperative_groups.h>

namespace cg = cooperative_groups;

#define TLEN 2048
#define NB   64
#define NH   256
#define NF   64
#define NCIN 16
#define NOUT 20
#define HB   (NH * NB)   // 16384 floats per h buffer
#define RING 8           // h0 ring depth (L0 may run up to RING-1 steps ahead)

__device__ __forceinline__ float sigf(float x) { return 1.0f / (1.0f + __expf(-x)); }
__device__ __forceinline__ float tanh_f(float x) {
    x = fminf(fmaxf(x, -15.0f), 15.0f);
    float e = __expf(2.0f * x);
    return (e - 1.0f) / (e + 1.0f);
}

// ---------------- Pass A: conv + relu, per-(f, t-quarter) partial sums for BN stats
__global__ __launch_bounds__(256) void conv_stats_kernel(
    const float* __restrict__ x, const float* __restrict__ cw, const float* __restrict__ cb,
    float* __restrict__ partials)
{
    const int blk = blockIdx.x;          // 256 blocks
    const int f = blk >> 2, tq = blk & 3;
    const int tid = threadIdx.x;

    float w[NCIN][3];
#pragma unroll
    for (int c = 0; c < NCIN; ++c) {
        w[c][0] = cw[(f * NCIN + c) * 3 + 0];
        w[c][1] = cw[(f * NCIN + c) * 3 + 1];
        w[c][2] = cw[(f * NCIN + c) * 3 + 2];
    }
    const float bias = cb[f];
    float s = 0.f, s2 = 0.f;

    for (int i = 0; i < 128; ++i) {
        int idx = tq * 32768 + i * 256 + tid;   // (B*T)/4 elements per block
        int b = idx >> 11;
        int t = idx & 2047;
        const float* xb = x + (size_t)b * NCIN * TLEN;
        float acc = bias;
#pragma unroll
        for (int c = 0; c < NCIN; ++c) {
            const float* xc = xb + (size_t)c * TLEN + t;
            float xm = (t > 0)        ? xc[-1] : 0.f;
            float x0 = xc[0];
            float xp = (t < TLEN - 1) ? xc[1]  : 0.f;
            acc = fmaf(xm, w[c][0], acc);
            acc = fmaf(x0, w[c][1], acc);
            acc = fmaf(xp, w[c][2], acc);
        }
        float y = fmaxf(acc, 0.f);
        s += y; s2 = fmaf(y, y, s2);
    }

    __shared__ float rs[256], rs2[256];
    rs[tid] = s; rs2[tid] = s2;
    __syncthreads();
    for (int off = 128; off > 0; off >>= 1) {
        if (tid < off) { rs[tid] += rs[tid + off]; rs2[tid] += rs2[tid + off]; }
        __syncthreads();
    }
    if (tid == 0) {
        partials[(f * 4 + tq) * 2 + 0] = rs[0];
        partials[(f * 4 + tq) * 2 + 1] = rs2[0];
    }
}

// ---------------- Pass B: conv + relu + BN affine, write feats[t][f][b]
__global__ __launch_bounds__(256) void conv_bn_feats_kernel(
    const float* __restrict__ x, const float* __restrict__ cw, const float* __restrict__ cb,
    const float* __restrict__ gamma, const float* __restrict__ beta,
    const float* __restrict__ partials, float* __restrict__ feats)
{
    const int t = blockIdx.x;            // 2048 blocks
    const int tid = threadIdx.x;
    const int b = tid & 63, fq = tid >> 6;

    __shared__ float sc[NF], sh[NF];
    if (tid < NF) {
        int f = tid;
        float s = 0.f, s2 = 0.f;
        for (int q = 0; q < 4; ++q) {
            s  += partials[(f * 4 + q) * 2 + 0];
            s2 += partials[(f * 4 + q) * 2 + 1];
        }
        const float inv_n = 1.0f / ((float)NB * (float)TLEN);
        float mean = s * inv_n;
        float var  = s2 * inv_n - mean * mean;
        float iv   = rsqrtf(var + 1e-5f);
        float scale = gamma[f] * iv;
        sc[f] = scale;
        sh[f] = beta[f] - mean * scale;
    }
    __syncthreads();

    float xr[NCIN][3];
    const float* xb = x + (size_t)b * NCIN * TLEN;
#pragma unroll
    for (int c = 0; c < NCIN; ++c) {
        const float* xc = xb + (size_t)c * TLEN + t;
        xr[c][0] = (t > 0)        ? xc[-1] : 0.f;
        xr[c][1] = xc[0];
        xr[c][2] = (t < TLEN - 1) ? xc[1]  : 0.f;
    }

    float* ft = feats + (size_t)t * (NF * NB);
    for (int fi = 0; fi < 16; ++fi) {
        int f = fq * 16 + fi;
        float acc = cb[f];
#pragma unroll
        for (int c = 0; c < NCIN; ++c) {
            acc = fmaf(xr[c][0], cw[(f * NCIN + c) * 3 + 0], acc);
            acc = fmaf(xr[c][1], cw[(f * NCIN + c) * 3 + 1], acc);
            acc = fmaf(xr[c][2], cw[(f * NCIN + c) * 3 + 2], acc);
        }
        float y = fmaxf(acc, 0.f);
        ft[f * NB + b] = fmaf(y, sc[f], sh[f]);
    }
}

#define QUAD() do { \
    a0 = fmaf(x0, w0.x, a0); a0 = fmaf(x1, w0.y, a0); a0 = fmaf(x2, w0.z, a0); a0 = fmaf(x3, w0.w, a0); \
    a1 = fmaf(x0, w1.x, a1); a1 = fmaf(x1, w1.y, a1); a1 = fmaf(x2, w1.z, a1); a1 = fmaf(x3, w1.w, a1); \
    a2 = fmaf(x0, w2.x, a2); a2 = fmaf(x1, w2.y, a2); a2 = fmaf(x2, w2.z, a2); a2 = fmaf(x3, w2.w, a2); \
    a3 = fmaf(x0, w3.x, a3); a3 = fmaf(x1, w3.y, a3); a3 = fmaf(x2, w3.z, a3); a3 = fmaf(x3, w3.w, a3); \
} while (0)

// ---------------- LSTM + FC kernel with decoupled flag-based sync
// Grid: 256 blocks x 256 threads (cooperative launch only to guarantee co-residency;
// the ONLY cg::sync is the one after flag init).
//   blocks [0,128):   layer-0, hidden units j0=blk*2      (K = 64 feats + 256 h0 = 320)
//   blocks [128,256): layer-1, hidden units j0=(blk-128)*2 (K = 256 h0 + 256 h1 = 512)
//   L1 blocks [128,148): additionally FC output row o=blk-128 for t=s-1
// Sync protocol (per-block epoch flags, agent-scope acquire/release atomics):
//   L0 step s: wait all flag0 >= s  AND all flag1 >= s-(RING-1)   [ring overwrite guard]
//              compute h0[s] -> ring slot s%RING, publish flag0[i]=s+1
//   L1 step s: wait all flag0 >= s+1 AND all flag1 >= s
//              FC(t=s-1), compute h1[s] -> slot s&1, publish flag1[i]=s+1
__global__ __launch_bounds__(256) void lstm_kernel(
    const float* __restrict__ feats,
    const float* __restrict__ wih0, const float* __restrict__ whh0,
    const float* __restrict__ bih0, const float* __restrict__ bhh0,
    const float* __restrict__ wih1, const float* __restrict__ whh1,
    const float* __restrict__ bih1, const float* __restrict__ bhh1,
    const float* __restrict__ fcw,  const float* __restrict__ fcb,
    float* __restrict__ h0, float* __restrict__ h1,
    int* __restrict__ flag0, int* __restrict__ flag1,
    float* __restrict__ out)
{
    cg::grid_group grid = cg::this_grid();
    const int blk = blockIdx.x;
    const int tid = threadIdx.x;
    const int b  = tid & 63;
    const int q  = tid >> 6;   // wave id 0..3
    const int u  = q & 1;      // which of the block's 2 hidden units
    const int kh = q >> 1;     // which K-half
    const bool isL1 = (blk >= 128);
    const int j0 = (isL1 ? blk - 128 : blk) * 2;

    __shared__ float  W[8 * 512];      // rows: [u*4+gate][k], stride 512
    __shared__ float  bias8[8];
    __shared__ float4 red4[2][64];
    __shared__ float  red1[4][64];

    // ---- load weights into LDS (once)
    for (int r = 0; r < 8; ++r) {
        int uu = r >> 2, g = r & 3;
        int grow = g * 256 + j0 + uu;   // PyTorch gate order i,f,g,o
        if (!isL1) {
            for (int k = tid; k < 320; k += 256)
                W[r * 512 + k] = (k < 64) ? wih0[grow * 64 + k] : whh0[grow * 256 + (k - 64)];
        } else {
            for (int k = tid; k < 512; k += 256)
                W[r * 512 + k] = (k < 256) ? wih1[grow * 256 + k] : whh1[grow * 256 + (k - 256)];
        }
    }
    if (tid < 8) {
        int r = tid, uu = r >> 2, g = r & 3;
        int grow = g * 256 + j0 + uu;
        bias8[r] = isL1 ? (bih1[grow] + bhh1[grow]) : (bih0[grow] + bhh0[grow]);
    }
    // ---- reset own flag + zero initial state (replay-safe: grid.sync below fences)
    if (tid == 0) {
        if (!isL1) __hip_atomic_store(&flag0[blk], 0, __ATOMIC_RELAXED, __HIP_MEMORY_SCOPE_AGENT);
        else       __hip_atomic_store(&flag1[blk - 128], 0, __ATOMIC_RELAXED, __HIP_MEMORY_SCOPE_AGENT);
    }
    if (tid < 128) {
        int uu = tid >> 6, bb = tid & 63;
        int j = j0 + uu;
        if (!isL1) h0[(RING - 1) * HB + j * 64 + bb] = 0.f;  // h0[-1] ring slot
        else       h1[1 * HB + j * 64 + bb] = 0.f;           // h1[-1] parity slot
    }
    float c_reg = 0.f;                                       // cell state, tid<128 threads own (u=q,b)
    __syncthreads();
    grid.sync();   // the only grid-wide barrier: publishes flag zeroing + init state

    const float4* W0v = (const float4*)(W + (u * 4 + 0) * 512);
    const float4* W1v = (const float4*)(W + (u * 4 + 1) * 512);
    const float4* W2v = (const float4*)(W + (u * 4 + 2) * 512);
    const float4* W3v = (const float4*)(W + (u * 4 + 3) * 512);

    if (!isL1) {
        // =============== layer 0 blocks ===============
        for (int s = 0; s < TLEN; ++s) {
            // wait: all flag0 >= s ; ring guard: all flag1 >= s-(RING-1)
            const int thrB = s - (RING - 1);
            for (;;) {
                int v; bool ok;
                if (tid < 128) { v = __hip_atomic_load(&flag0[tid], __ATOMIC_ACQUIRE, __HIP_MEMORY_SCOPE_AGENT); ok = v >= s; }
                else           { v = __hip_atomic_load(&flag1[tid - 128], __ATOMIC_ACQUIRE, __HIP_MEMORY_SCOPE_AGENT); ok = v >= thrB; }
                if (__syncthreads_count(ok) == 256) break;
                __builtin_amdgcn_s_sleep(1);
            }
            const float* h0prev = h0 + ((s + RING - 1) % RING) * HB;   // step s-1
            float a0, a1, a2, a3;
            if (kh == 0) {
                a0 = bias8[u * 4 + 0]; a1 = bias8[u * 4 + 1];
                a2 = bias8[u * 4 + 2]; a3 = bias8[u * 4 + 3];
                const float* fp = feats + (size_t)s * (NF * NB) + b;
#pragma unroll 4
                for (int k4 = 0; k4 < 16; ++k4) {            // k 0..63 : conv feats
                    float4 w0 = W0v[k4], w1 = W1v[k4], w2 = W2v[k4], w3 = W3v[k4];
                    float x0 = fp[(4 * k4 + 0) * 64], x1 = fp[(4 * k4 + 1) * 64];
                    float x2 = fp[(4 * k4 + 2) * 64], x3 = fp[(4 * k4 + 3) * 64];
                    QUAD();
                }
                const float* hp = h0prev + b;
#pragma unroll 4
                for (int k4 = 16; k4 < 40; ++k4) {           // k 64..159 : h0 rows 0..95
                    float4 w0 = W0v[k4], w1 = W1v[k4], w2 = W2v[k4], w3 = W3v[k4];
                    int hk = 4 * k4 - 64;
                    float x0 = hp[(hk + 0) * 64], x1 = hp[(hk + 1) * 64];
                    float x2 = hp[(hk + 2) * 64], x3 = hp[(hk + 3) * 64];
                    QUAD();
                }
            } else {
                a0 = a1 = a2 = a3 = 0.f;
                const float* hp = h0prev + b;
#pragma unroll 4
                for (int k4 = 40; k4 < 80; ++k4) {           // k 160..319 : h0 rows 96..255
                    float4 w0 = W0v[k4], w1 = W1v[k4], w2 = W2v[k4], w3 = W3v[k4];
                    int hk = 4 * k4 - 64;
                    float x0 = hp[(hk + 0) * 64], x1 = hp[(hk + 1) * 64];
                    float x2 = hp[(hk + 2) * 64], x3 = hp[(hk + 3) * 64];
                    QUAD();
                }
                red4[u][b] = make_float4(a0, a1, a2, a3);
            }
            __syncthreads();
            if (kh == 0) {
                float4 r = red4[u][b];
                float gi = a0 + r.x, gf = a1 + r.y, gg = a2 + r.z, go = a3 + r.w;
                int j = j0 + u;
                float i_ = sigf(gi), f_ = sigf(gf), g_ = tanh_f(gg), o_ = sigf(go);
                c_reg = fmaf(f_, c_reg, i_ * g_);
                float h = o_ * tanh_f(c_reg);
                h0[(s % RING) * HB + j * 64 + b] = h;
            }
            __syncthreads();   // each wave drains vmcnt before the release below
            if (tid == 0)
                __hip_atomic_store(&flag0[blk], s + 1, __ATOMIC_RELEASE, __HIP_MEMORY_SCOPE_AGENT);
        }
    } else {
        // =============== layer 1 blocks ===============
        const int jb = blk - 128;
        const bool doFC = (jb < NOUT);
        for (int s = 0; s < TLEN; ++s) {
            // wait: all flag0 >= s+1 (h0[s] ready) ; all flag1 >= s (h1[s-1] ready)
            for (;;) {
                int v; bool ok;
                if (tid < 128) { v = __hip_atomic_load(&flag0[tid], __ATOMIC_ACQUIRE, __HIP_MEMORY_SCOPE_AGENT); ok = v >= s + 1; }
                else           { v = __hip_atomic_load(&flag1[tid - 128], __ATOMIC_ACQUIRE, __HIP_MEMORY_SCOPE_AGENT); ok = v >= s; }
                if (__syncthreads_count(ok) == 256) break;
                __builtin_amdgcn_s_sleep(1);
            }
            const float* h0cur  = h0 + (s % RING) * HB;      // step s
            const float* h1prev = h1 + ((s + 1) & 1) * HB;   // step s-1

            if (doFC && s >= 1) {                            // FC row jb, t=s-1
                const float* fw = fcw + jb * NH + q * 64;
                const float* hp = h1prev + q * 64 * NB + b;
                float acc = 0.f;
#pragma unroll 4
                for (int k = 0; k < 64; ++k) acc = fmaf(hp[k * 64], fw[k], acc);
                red1[q][b] = acc;
                __syncthreads();
                if (q == 0) {
                    float sres = red1[0][b] + red1[1][b] + red1[2][b] + red1[3][b] + fcb[jb];
                    out[((size_t)b * NOUT + jb) * TLEN + (s - 1)] = sres;
                }
            }

            const float* Xs = ((kh == 0) ? h0cur : h1prev) + b;
            const int kbase = kh * 64;
            float a0, a1, a2, a3;
            if (kh == 0) {
                a0 = bias8[u * 4 + 0]; a1 = bias8[u * 4 + 1];
                a2 = bias8[u * 4 + 2]; a3 = bias8[u * 4 + 3];
            } else { a0 = a1 = a2 = a3 = 0.f; }
#pragma unroll 4
            for (int k4 = 0; k4 < 64; ++k4) {
                float4 w0 = W0v[kbase + k4], w1 = W1v[kbase + k4];
                float4 w2 = W2v[kbase + k4], w3 = W3v[kbase + k4];
                float x0 = Xs[(4 * k4 + 0) * 64], x1 = Xs[(4 * k4 + 1) * 64];
                float x2 = Xs[(4 * k4 + 2) * 64], x3 = Xs[(4 * k4 + 3) * 64];
                QUAD();
            }
            if (kh == 1) red4[u][b] = make_float4(a0, a1, a2, a3);
            __syncthreads();
            if (kh == 0) {
                float4 r = red4[u][b];
                float gi = a0 + r.x, gf = a1 + r.y, gg = a2 + r.z, go = a3 + r.w;
                int j = j0 + u;
                float i_ = sigf(gi), f_ = sigf(gf), g_ = tanh_f(gg), o_ = sigf(go);
                c_reg = fmaf(f_, c_reg, i_ * g_);
                float h = o_ * tanh_f(c_reg);
                h1[(s & 1) * HB + j * 64 + b] = h;
            }
            __syncthreads();   // each wave drains vmcnt before the release below
            if (tid == 0)
                __hip_atomic_store(&flag1[jb], s + 1, __ATOMIC_RELEASE, __HIP_MEMORY_SCOPE_AGENT);
        }
        // epilogue: FC for t = TLEN-1 (needs all h1[TLEN-1])
        if (doFC) {
            for (;;) {
                int v = 0x7fffffff;
                if (tid < 128) v = __hip_atomic_load(&flag1[tid], __ATOMIC_ACQUIRE, __HIP_MEMORY_SCOPE_AGENT);
                if (__syncthreads_count(v >= TLEN) == 256) break;
                __builtin_amdgcn_s_sleep(1);
            }
            const float* hlast = h1 + ((TLEN - 1) & 1) * HB;
            const float* fw = fcw + jb * NH + q * 64;
            const float* hp = hlast + q * 64 * NB + b;
            float acc = 0.f;
#pragma unroll 4
            for (int k = 0; k < 64; ++k) acc = fmaf(hp[k * 64], fw[k], acc);
            red1[q][b] = acc;
            __syncthreads();
            if (q == 0) {
                float sres = red1[0][b] + red1[1][b] + red1[2][b] + red1[3][b] + fcb[jb];
                out[((size_t)b * NOUT + jb) * TLEN + (TLEN - 1)] = sres;
            }
        }
    }
}

extern "C" void kernel_launch(void* const* d_in, const int* in_sizes, int n_in,
                              void* d_out, int out_size, void* d_ws, size_t ws_size,
                              hipStream_t stream) {
    (void)in_sizes; (void)n_in; (void)out_size; (void)ws_size;
    const float* x      = (const float*)d_in[0];
    const float* conv_w = (const float*)d_in[1];
    const float* conv_b = (const float*)d_in[2];
    const float* gamma  = (const float*)d_in[3];
    const float* beta   = (const float*)d_in[4];
    const float* wih0   = (const float*)d_in[5];
    const float* whh0   = (const float*)d_in[6];
    const float* bih0   = (const float*)d_in[7];
    const float* bhh0   = (const float*)d_in[8];
    const float* wih1   = (const float*)d_in[9];
    const float* whh1   = (const float*)d_in[10];
    const float* bih1   = (const float*)d_in[11];
    const float* bhh1   = (const float*)d_in[12];
    const float* fcw    = (const float*)d_in[13];
    const float* fcb    = (const float*)d_in[14];
    float* out = (float*)d_out;

    char* ws = (char*)d_ws;
    float* feats    = (float*)(ws);                      // 2048*64*64*4 = 33,554,432 B
    float* partials = (float*)(ws + 33554432);           // 512 floats   (2,048 B)
    float* h0       = (float*)(ws + 33556480);           // RING*16384*4 = 524,288 B
    float* h1       = (float*)(ws + 34080768);           // 2*16384*4    = 131,072 B
    int*   flag0    = (int*)  (ws + 34211840);           // 128 ints
    int*   flag1    = flag0 + 128;                       // 128 ints

    hipLaunchKernelGGL(conv_stats_kernel, dim3(256), dim3(256), 0, stream,
                       x, conv_w, conv_b, partials);
    hipLaunchKernelGGL(conv_bn_feats_kernel, dim3(2048), dim3(256), 0, stream,
                       x, conv_w, conv_b, gamma, beta, partials, feats);

    void* args[] = { (void*)&feats,
                     (void*)&wih0, (void*)&whh0, (void*)&bih0, (void*)&bhh0,
                     (void*)&wih1, (void*)&whh1, (void*)&bih1, (void*)&bhh1,
                     (void*)&fcw,  (void*)&fcb,
                     (void*)&h0, (void*)&h1, (void*)&flag0, (void*)&flag1,
                     (void*)&out };
    hipLaunchCooperativeKernel((void*)lstm_kernel, dim3(256), dim3(256), args, 0, stream);
}

// Round 3
// 47182.141 us; speedup vs baseline: 2.3558x; 2.3558x over previous
//
#include <hip/hip_runtime.h>
#include <hip/hip_cooperative_groups.h>

namespace cg = cooperative_groups;

#define TLEN 2048
#define NB   64
#define NH   256
#define NF   64
#define NCIN 16
#define NOUT 20
#define HB   (NH * NB)   // 16384 floats per h buffer
#define RING 8           // h0 ring depth (L0 may run up to RING-1 steps ahead)

// LLC-coherent (sc1) access helpers: never stale in per-XCD L2, no fences needed.
#define HL(p)    __hip_atomic_load((p),      __ATOMIC_RELAXED, __HIP_MEMORY_SCOPE_AGENT)
#define HS(p, v) __hip_atomic_store((p), (v), __ATOMIC_RELAXED, __HIP_MEMORY_SCOPE_AGENT)

__device__ __forceinline__ float sigf(float x) { return 1.0f / (1.0f + __expf(-x)); }
__device__ __forceinline__ float tanh_f(float x) {
    x = fminf(fmaxf(x, -15.0f), 15.0f);
    float e = __expf(2.0f * x);
    return (e - 1.0f) / (e + 1.0f);
}

// ---------------- Pass A: conv + relu, per-(f, t-quarter) partial sums for BN stats
__global__ __launch_bounds__(256) void conv_stats_kernel(
    const float* __restrict__ x, const float* __restrict__ cw, const float* __restrict__ cb,
    float* __restrict__ partials)
{
    const int blk = blockIdx.x;          // 256 blocks
    const int f = blk >> 2, tq = blk & 3;
    const int tid = threadIdx.x;

    float w[NCIN][3];
#pragma unroll
    for (int c = 0; c < NCIN; ++c) {
        w[c][0] = cw[(f * NCIN + c) * 3 + 0];
        w[c][1] = cw[(f * NCIN + c) * 3 + 1];
        w[c][2] = cw[(f * NCIN + c) * 3 + 2];
    }
    const float bias = cb[f];
    float s = 0.f, s2 = 0.f;

    for (int i = 0; i < 128; ++i) {
        int idx = tq * 32768 + i * 256 + tid;   // (B*T)/4 elements per block
        int b = idx >> 11;
        int t = idx & 2047;
        const float* xb = x + (size_t)b * NCIN * TLEN;
        float acc = bias;
#pragma unroll
        for (int c = 0; c < NCIN; ++c) {
            const float* xc = xb + (size_t)c * TLEN + t;
            float xm = (t > 0)        ? xc[-1] : 0.f;
            float x0 = xc[0];
            float xp = (t < TLEN - 1) ? xc[1]  : 0.f;
            acc = fmaf(xm, w[c][0], acc);
            acc = fmaf(x0, w[c][1], acc);
            acc = fmaf(xp, w[c][2], acc);
        }
        float y = fmaxf(acc, 0.f);
        s += y; s2 = fmaf(y, y, s2);
    }

    __shared__ float rs[256], rs2[256];
    rs[tid] = s; rs2[tid] = s2;
    __syncthreads();
    for (int off = 128; off > 0; off >>= 1) {
        if (tid < off) { rs[tid] += rs[tid + off]; rs2[tid] += rs2[tid + off]; }
        __syncthreads();
    }
    if (tid == 0) {
        partials[(f * 4 + tq) * 2 + 0] = rs[0];
        partials[(f * 4 + tq) * 2 + 1] = rs2[0];
    }
}

// ---------------- Pass B: conv + relu + BN affine, write feats[t][f][b]
__global__ __launch_bounds__(256) void conv_bn_feats_kernel(
    const float* __restrict__ x, const float* __restrict__ cw, const float* __restrict__ cb,
    const float* __restrict__ gamma, const float* __restrict__ beta,
    const float* __restrict__ partials, float* __restrict__ feats)
{
    const int t = blockIdx.x;            // 2048 blocks
    const int tid = threadIdx.x;
    const int b = tid & 63, fq = tid >> 6;

    __shared__ float sc[NF], sh[NF];
    if (tid < NF) {
        int f = tid;
        float s = 0.f, s2 = 0.f;
        for (int q = 0; q < 4; ++q) {
            s  += partials[(f * 4 + q) * 2 + 0];
            s2 += partials[(f * 4 + q) * 2 + 1];
        }
        const float inv_n = 1.0f / ((float)NB * (float)TLEN);
        float mean = s * inv_n;
        float var  = s2 * inv_n - mean * mean;
        float iv   = rsqrtf(var + 1e-5f);
        float scale = gamma[f] * iv;
        sc[f] = scale;
        sh[f] = beta[f] - mean * scale;
    }
    __syncthreads();

    float xr[NCIN][3];
    const float* xb = x + (size_t)b * NCIN * TLEN;
#pragma unroll
    for (int c = 0; c < NCIN; ++c) {
        const float* xc = xb + (size_t)c * TLEN + t;
        xr[c][0] = (t > 0)        ? xc[-1] : 0.f;
        xr[c][1] = xc[0];
        xr[c][2] = (t < TLEN - 1) ? xc[1]  : 0.f;
    }

    float* ft = feats + (size_t)t * (NF * NB);
    for (int fi = 0; fi < 16; ++fi) {
        int f = fq * 16 + fi;
        float acc = cb[f];
#pragma unroll
        for (int c = 0; c < NCIN; ++c) {
            acc = fmaf(xr[c][0], cw[(f * NCIN + c) * 3 + 0], acc);
            acc = fmaf(xr[c][1], cw[(f * NCIN + c) * 3 + 1], acc);
            acc = fmaf(xr[c][2], cw[(f * NCIN + c) * 3 + 2], acc);
        }
        float y = fmaxf(acc, 0.f);
        ft[f * NB + b] = fmaf(y, sc[f], sh[f]);
    }
}

#define QUAD() do { \
    a0 = fmaf(x0, w0.x, a0); a0 = fmaf(x1, w0.y, a0); a0 = fmaf(x2, w0.z, a0); a0 = fmaf(x3, w0.w, a0); \
    a1 = fmaf(x0, w1.x, a1); a1 = fmaf(x1, w1.y, a1); a1 = fmaf(x2, w1.z, a1); a1 = fmaf(x3, w1.w, a1); \
    a2 = fmaf(x0, w2.x, a2); a2 = fmaf(x1, w2.y, a2); a2 = fmaf(x2, w2.z, a2); a2 = fmaf(x3, w2.w, a2); \
    a3 = fmaf(x0, w3.x, a3); a3 = fmaf(x1, w3.y, a3); a3 = fmaf(x2, w3.z, a3); a3 = fmaf(x3, w3.w, a3); \
} while (0)

// ---------------- LSTM + FC kernel, decoupled flag sync, LLC-coherent data path
// Grid: 256 blocks x 256 threads (cooperative launch only for co-residency;
// the only cg::sync is after flag re-zeroing).
//   blocks [0,128):   layer-0, hidden units j0=blk*2      (K = 64 feats + 256 h0 = 320)
//   blocks [128,256): layer-1, hidden units j0=(blk-128)*2 (K = 256 h0 + 256 h1 = 512)
//   L1 blocks [128,148): additionally FC output row o=blk-128 for t=s-1
// Protocol: producers publish via __syncthreads (vmcnt drain) + tid0 RELEASE flag store.
//   Consumers spin with RELAXED loads (sc1 -> LLC, no invalidation) + value cache;
//   all h0/h1 data accesses are relaxed agent atomics (sc1) so no acquire is needed.
__global__ __launch_bounds__(256) void lstm_kernel(
    const float* __restrict__ feats,
    const float* __restrict__ wih0, const float* __restrict__ whh0,
    const float* __restrict__ bih0, const float* __restrict__ bhh0,
    const float* __restrict__ wih1, const float* __restrict__ whh1,
    const float* __restrict__ bih1, const float* __restrict__ bhh1,
    const float* __restrict__ fcw,  const float* __restrict__ fcb,
    float* __restrict__ h0, float* __restrict__ h1,
    int* __restrict__ flag0, int* __restrict__ flag1,
    float* __restrict__ out)
{
    cg::grid_group grid = cg::this_grid();
    const int blk = blockIdx.x;
    const int tid = threadIdx.x;
    const int b  = tid & 63;
    const int q  = tid >> 6;   // wave id 0..3
    const int u  = q & 1;      // which of the block's 2 hidden units
    const int kh = q >> 1;     // which K-half
    const bool isL1 = (blk >= 128);
    const int j0 = (isL1 ? blk - 128 : blk) * 2;

    __shared__ float  W[8 * 512];      // rows: [u*4+gate][k], stride 512
    __shared__ float  bias8[8];
    __shared__ float4 red4[2][64];
    __shared__ float  red1[4][64];

    // ---- load weights into LDS (once)
    for (int r = 0; r < 8; ++r) {
        int uu = r >> 2, g = r & 3;
        int grow = g * 256 + j0 + uu;   // PyTorch gate order i,f,g,o
        if (!isL1) {
            for (int k = tid; k < 320; k += 256)
                W[r * 512 + k] = (k < 64) ? wih0[grow * 64 + k] : whh0[grow * 256 + (k - 64)];
        } else {
            for (int k = tid; k < 512; k += 256)
                W[r * 512 + k] = (k < 256) ? wih1[grow * 256 + k] : whh1[grow * 256 + (k - 256)];
        }
    }
    if (tid < 8) {
        int r = tid, uu = r >> 2, g = r & 3;
        int grow = g * 256 + j0 + uu;
        bias8[r] = isL1 ? (bih1[grow] + bhh1[grow]) : (bih0[grow] + bhh0[grow]);
    }
    // ---- reset own flag + zero initial state (grid.sync below publishes globally)
    if (tid == 0) {
        if (!isL1) HS(&flag0[blk], 0);
        else       HS(&flag1[blk - 128], 0);
    }
    if (tid < 128) {
        int uu = tid >> 6, bb = tid & 63;
        int j = j0 + uu;
        if (!isL1) HS(&h0[(RING - 1) * HB + j * 64 + bb], 0.f);  // h0[-1] ring slot
        else       HS(&h1[1 * HB + j * 64 + bb], 0.f);           // h1[-1] parity slot
    }
    float c_reg = 0.f;                 // cell state, tid<128 threads own (u=q,b)
    int fcache = 0;                    // per-thread cached flag value (monotone)
    __syncthreads();
    grid.sync();   // the only grid-wide barrier: publishes flag zeroing + init state

    const float4* W0v = (const float4*)(W + (u * 4 + 0) * 512);
    const float4* W1v = (const float4*)(W + (u * 4 + 1) * 512);
    const float4* W2v = (const float4*)(W + (u * 4 + 2) * 512);
    const float4* W3v = (const float4*)(W + (u * 4 + 3) * 512);

    if (!isL1) {
        // =============== layer 0 blocks ===============
        for (int s = 0; s < TLEN; ++s) {
            // wait: all flag0 >= s ; ring guard: all flag1 >= s-(RING-1)
            const int thrB = s - (RING - 1);
            for (;;) {
                bool ok;
                if (tid < 128) { if (fcache < s)    fcache = HL(&flag0[tid]);       ok = fcache >= s; }
                else           { if (fcache < thrB) fcache = HL(&flag1[tid - 128]); ok = fcache >= thrB; }
                if (__syncthreads_count(ok) == 256) break;
                __builtin_amdgcn_s_sleep(2);
            }
            const float* h0prev = h0 + ((s + RING - 1) % RING) * HB;   // step s-1
            float a0, a1, a2, a3;
            if (kh == 0) {
                a0 = bias8[u * 4 + 0]; a1 = bias8[u * 4 + 1];
                a2 = bias8[u * 4 + 2]; a3 = bias8[u * 4 + 3];
                const float* fp = feats + (size_t)s * (NF * NB) + b;
#pragma unroll 4
                for (int k4 = 0; k4 < 16; ++k4) {            // k 0..63 : conv feats (plain cached)
                    float4 w0 = W0v[k4], w1 = W1v[k4], w2 = W2v[k4], w3 = W3v[k4];
                    float x0 = fp[(4 * k4 + 0) * 64], x1 = fp[(4 * k4 + 1) * 64];
                    float x2 = fp[(4 * k4 + 2) * 64], x3 = fp[(4 * k4 + 3) * 64];
                    QUAD();
                }
                const float* hp = h0prev + b;
#pragma unroll 8
                for (int k4 = 16; k4 < 40; ++k4) {           // k 64..159 : h0 rows 0..95 (sc1)
                    float4 w0 = W0v[k4], w1 = W1v[k4], w2 = W2v[k4], w3 = W3v[k4];
                    int hk = 4 * k4 - 64;
                    float x0 = HL(hp + (hk + 0) * 64), x1 = HL(hp + (hk + 1) * 64);
                    float x2 = HL(hp + (hk + 2) * 64), x3 = HL(hp + (hk + 3) * 64);
                    QUAD();
                }
            } else {
                a0 = a1 = a2 = a3 = 0.f;
                const float* hp = h0prev + b;
#pragma unroll 8
                for (int k4 = 40; k4 < 80; ++k4) {           // k 160..319 : h0 rows 96..255 (sc1)
                    float4 w0 = W0v[k4], w1 = W1v[k4], w2 = W2v[k4], w3 = W3v[k4];
                    int hk = 4 * k4 - 64;
                    float x0 = HL(hp + (hk + 0) * 64), x1 = HL(hp + (hk + 1) * 64);
                    float x2 = HL(hp + (hk + 2) * 64), x3 = HL(hp + (hk + 3) * 64);
                    QUAD();
                }
                red4[u][b] = make_float4(a0, a1, a2, a3);
            }
            __syncthreads();
            if (kh == 0) {
                float4 r = red4[u][b];
                float gi = a0 + r.x, gf = a1 + r.y, gg = a2 + r.z, go = a3 + r.w;
                int j = j0 + u;
                float i_ = sigf(gi), f_ = sigf(gf), g_ = tanh_f(gg), o_ = sigf(go);
                c_reg = fmaf(f_, c_reg, i_ * g_);
                float h = o_ * tanh_f(c_reg);
                HS(&h0[(s % RING) * HB + j * 64 + b], h);
            }
            __syncthreads();   // drains all waves' vmcnt (sc1 stores complete at LLC)
            if (tid == 0)
                __hip_atomic_store(&flag0[blk], s + 1, __ATOMIC_RELEASE, __HIP_MEMORY_SCOPE_AGENT);
        }
    } else {
        // =============== layer 1 blocks ===============
        const int jb = blk - 128;
        const bool doFC = (jb < NOUT);
        for (int s = 0; s < TLEN; ++s) {
            // wait: all flag0 >= s+1 (h0[s] ready) ; all flag1 >= s (h1[s-1] ready)
            for (;;) {
                bool ok;
                if (tid < 128) { if (fcache < s + 1) fcache = HL(&flag0[tid]);       ok = fcache >= s + 1; }
                else           { if (fcache < s)     fcache = HL(&flag1[tid - 128]); ok = fcache >= s; }
                if (__syncthreads_count(ok) == 256) break;
                __builtin_amdgcn_s_sleep(2);
            }
            const float* h0cur  = h0 + (s % RING) * HB;      // step s
            const float* h1prev = h1 + ((s + 1) & 1) * HB;   // step s-1

            if (doFC && s >= 1) {                            // FC row jb, t=s-1
                const float* fw = fcw + jb * NH + q * 64;
                const float* hp = h1prev + q * 64 * NB + b;
                float acc = 0.f;
#pragma unroll 8
                for (int k = 0; k < 64; ++k) acc = fmaf(HL(hp + k * 64), fw[k], acc);
                red1[q][b] = acc;
                __syncthreads();
                if (q == 0) {
                    float sres = red1[0][b] + red1[1][b] + red1[2][b] + red1[3][b] + fcb[jb];
                    out[((size_t)b * NOUT + jb) * TLEN + (s - 1)] = sres;
                }
            }

            const float* Xs = ((kh == 0) ? h0cur : h1prev) + b;
            const int kbase = kh * 64;
            float a0, a1, a2, a3;
            if (kh == 0) {
                a0 = bias8[u * 4 + 0]; a1 = bias8[u * 4 + 1];
                a2 = bias8[u * 4 + 2]; a3 = bias8[u * 4 + 3];
            } else { a0 = a1 = a2 = a3 = 0.f; }
#pragma unroll 8
            for (int k4 = 0; k4 < 64; ++k4) {
                float4 w0 = W0v[kbase + k4], w1 = W1v[kbase + k4];
                float4 w2 = W2v[kbase + k4], w3 = W3v[kbase + k4];
                float x0 = HL(Xs + (4 * k4 + 0) * 64), x1 = HL(Xs + (4 * k4 + 1) * 64);
                float x2 = HL(Xs + (4 * k4 + 2) * 64), x3 = HL(Xs + (4 * k4 + 3) * 64);
                QUAD();
            }
            if (kh == 1) red4[u][b] = make_float4(a0, a1, a2, a3);
            __syncthreads();
            if (kh == 0) {
                float4 r = red4[u][b];
                float gi = a0 + r.x, gf = a1 + r.y, gg = a2 + r.z, go = a3 + r.w;
                int j = j0 + u;
                float i_ = sigf(gi), f_ = sigf(gf), g_ = tanh_f(gg), o_ = sigf(go);
                c_reg = fmaf(f_, c_reg, i_ * g_);
                float h = o_ * tanh_f(c_reg);
                HS(&h1[(s & 1) * HB + j * 64 + b], h);
            }
            __syncthreads();   // drains all waves' vmcnt (sc1 stores complete at LLC)
            if (tid == 0)
                __hip_atomic_store(&flag1[jb], s + 1, __ATOMIC_RELEASE, __HIP_MEMORY_SCOPE_AGENT);
        }
        // epilogue: FC for t = TLEN-1 (needs all h1[TLEN-1])
        if (doFC) {
            for (;;) {
                int v = 0x7fffffff;
                if (tid < 128) v = HL(&flag1[tid]);
                if (__syncthreads_count(v >= TLEN) == 256) break;
                __builtin_amdgcn_s_sleep(2);
            }
            const float* hlast = h1 + ((TLEN - 1) & 1) * HB;
            const float* fw = fcw + jb * NH + q * 64;
            const float* hp = hlast + q * 64 * NB + b;
            float acc = 0.f;
#pragma unroll 8
            for (int k = 0; k < 64; ++k) acc = fmaf(HL(hp + k * 64), fw[k], acc);
            red1[q][b] = acc;
            __syncthreads();
            if (q == 0) {
                float sres = red1[0][b] + red1[1][b] + red1[2][b] + red1[3][b] + fcb[jb];
                out[((size_t)b * NOUT + jb) * TLEN + (TLEN - 1)] = sres;
            }
        }
    }
}

extern "C" void kernel_launch(void* const* d_in, const int* in_sizes, int n_in,
                              void* d_out, int out_size, void* d_ws, size_t ws_size,
                              hipStream_t stream) {
    (void)in_sizes; (void)n_in; (void)out_size; (void)ws_size;
    const float* x      = (const float*)d_in[0];
    const float* conv_w = (const float*)d_in[1];
    const float* conv_b = (const float*)d_in[2];
    const float* gamma  = (const float*)d_in[3];
    const float* beta   = (const float*)d_in[4];
    const float* wih0   = (const float*)d_in[5];
    const float* whh0   = (const float*)d_in[6];
    const float* bih0   = (const float*)d_in[7];
    const float* bhh0   = (const float*)d_in[8];
    const float* wih1   = (const float*)d_in[9];
    const float* whh1   = (const float*)d_in[10];
    const float* bih1   = (const float*)d_in[11];
    const float* bhh1   = (const float*)d_in[12];
    const float* fcw    = (const float*)d_in[13];
    const float* fcb    = (const float*)d_in[14];
    float* out = (float*)d_out;

    char* ws = (char*)d_ws;
    float* feats    = (float*)(ws);                      // 2048*64*64*4 = 33,554,432 B
    float* partials = (float*)(ws + 33554432);           // 512 floats   (2,048 B)
    float* h0       = (float*)(ws + 33556480);           // RING*16384*4 = 524,288 B
    float* h1       = (float*)(ws + 34080768);           // 2*16384*4    = 131,072 B
    int*   flag0    = (int*)  (ws + 34211840);           // 128 ints
    int*   flag1    = flag0 + 128;                       // 128 ints

    hipLaunchKernelGGL(conv_stats_kernel, dim3(256), dim3(256), 0, stream,
                       x, conv_w, conv_b, partials);
    hipLaunchKernelGGL(conv_bn_feats_kernel, dim3(2048), dim3(256), 0, stream,
                       x, conv_w, conv_b, gamma, beta, partials, feats);

    void* args[] = { (void*)&feats,
                     (void*)&wih0, (void*)&whh0, (void*)&bih0, (void*)&bhh0,
                     (void*)&wih1, (void*)&whh1, (void*)&bih1, (void*)&bhh1,
                     (void*)&fcw,  (void*)&fcb,
                     (void*)&h0, (void*)&h1, (void*)&flag0, (void*)&flag1,
                     (void*)&out };
    hipLaunchCooperativeKernel((void*)lstm_kernel, dim3(256), dim3(256), args, 0, stream);
}